// Round 1
// baseline (1066.357 us; speedup 1.0000x reference)
//
#include <hip/hip_runtime.h>
#include <math.h>

#define NN 2048
#define TT 32
#define FIN 5
#define HH 64
#define G4 256     // 4*H
#define GATH 16

// ---------- helpers ----------
__device__ __forceinline__ float sigf(float x) {
    return 1.0f / (1.0f + __expf(-x));
}
__device__ __forceinline__ float tanh_fast(float x) {
    x = fminf(fmaxf(x, -15.0f), 15.0f);
    float t = __expf(2.0f * x);
    return (t - 1.0f) / (t + 1.0f);
}

// ---------- fused 2-layer LSTM ----------
// grid 256 blocks x 512 threads; 8 nodes per block.
// waves 0-3 (tid<256): layer-0 gate workers + layer-0 combine
// waves 4-7 (tid>=256): layer-1 gate workers + layer-1 combine
// layer-1 is pipelined one step behind layer-0 (33 iterations total).
#define LNB 8
__global__ __launch_bounds__(512, 2) void k_lstm(
    const float* __restrict__ inputs,
    const float* __restrict__ w_ih0, const float* __restrict__ w_hh0,
    const float* __restrict__ b_ih0, const float* __restrict__ b_hh0,
    const float* __restrict__ w_ih1, const float* __restrict__ w_hh1,
    const float* __restrict__ b_ih1, const float* __restrict__ b_hh1,
    float* __restrict__ x_out)
{
    __shared__ float x_lds[LNB * TT * FIN];   // 1280
    __shared__ float h0_lds[LNB * HH];        // 512
    __shared__ float h1_lds[LNB * HH];        // 512
    __shared__ float g0_lds[LNB * G4];        // 2048  [nb][g]
    __shared__ float g1_lds[LNB * G4];        // 2048

    const int tid = threadIdx.x;
    const int n0 = blockIdx.x * LNB;
    const bool isL1 = (tid >= 256);
    const int g = tid & 255;

    // stage inputs for this block's 8 nodes (contiguous 1280 floats)
    for (int idx = tid; idx < LNB * TT * FIN; idx += 512)
        x_lds[idx] = inputs[n0 * (TT * FIN) + idx];
    for (int idx = tid; idx < LNB * HH; idx += 512) {
        h0_lds[idx] = 0.0f;
        h1_lds[idx] = 0.0f;
    }

    // per-thread weights in registers
    float wih0r0 = 0.f, wih0r1 = 0.f, wih0r2 = 0.f, wih0r3 = 0.f, wih0r4 = 0.f;
    float4 whh4[16];     // w_hh row (either layer)
    float4 wih14[16];    // w_ih1 row (layer 1 only)
    float bias;
    if (!isL1) {
        wih0r0 = w_ih0[g * FIN + 0];
        wih0r1 = w_ih0[g * FIN + 1];
        wih0r2 = w_ih0[g * FIN + 2];
        wih0r3 = w_ih0[g * FIN + 3];
        wih0r4 = w_ih0[g * FIN + 4];
        const float4* p = (const float4*)(w_hh0 + g * HH);
        #pragma unroll
        for (int k4 = 0; k4 < 16; ++k4) whh4[k4] = p[k4];
        #pragma unroll
        for (int k4 = 0; k4 < 16; ++k4) wih14[k4] = make_float4(0.f, 0.f, 0.f, 0.f);
        bias = b_ih0[g] + b_hh0[g];
    } else {
        const float4* p1 = (const float4*)(w_ih1 + g * HH);
        #pragma unroll
        for (int k4 = 0; k4 < 16; ++k4) wih14[k4] = p1[k4];
        const float4* p2 = (const float4*)(w_hh1 + g * HH);
        #pragma unroll
        for (int k4 = 0; k4 < 16; ++k4) whh4[k4] = p2[k4];
        bias = b_ih1[g] + b_hh1[g];
    }

    // combine-phase mapping: this thread owns cells (cnb, ck) and (cnb, ck+32)
    const int cnb = g >> 5;        // 0..7
    const int ck = g & 31;         // 0..31
    float c_s0 = 0.0f, c_s1 = 0.0f;

    __syncthreads();

    for (int it = 0; it <= TT; ++it) {
        // ---- gate phase ----
        if (!isL1) {
            if (it < TT) {
                for (int nb = 0; nb < LNB; ++nb) {
                    const float* xl = &x_lds[nb * (TT * FIN) + it * FIN];
                    float a = bias + wih0r0 * xl[0] + wih0r1 * xl[1] +
                              wih0r2 * xl[2] + wih0r3 * xl[3] + wih0r4 * xl[4];
                    const float4* hv = (const float4*)&h0_lds[nb * HH];
                    float s = 0.0f;
                    #pragma unroll
                    for (int k4 = 0; k4 < 16; ++k4) {
                        float4 h4 = hv[k4];
                        s += whh4[k4].x * h4.x + whh4[k4].y * h4.y +
                             whh4[k4].z * h4.z + whh4[k4].w * h4.w;
                    }
                    g0_lds[nb * G4 + g] = a + s;
                }
            }
        } else {
            if (it >= 1) {
                for (int nb = 0; nb < LNB; ++nb) {
                    const float4* xv = (const float4*)&h0_lds[nb * HH];
                    const float4* hv = (const float4*)&h1_lds[nb * HH];
                    float a = bias;
                    float s = 0.0f;
                    #pragma unroll
                    for (int k4 = 0; k4 < 16; ++k4) {
                        float4 x4 = xv[k4];
                        float4 h4 = hv[k4];
                        a += wih14[k4].x * x4.x + wih14[k4].y * x4.y +
                             wih14[k4].z * x4.z + wih14[k4].w * x4.w;
                        s += whh4[k4].x * h4.x + whh4[k4].y * h4.y +
                             whh4[k4].z * h4.z + whh4[k4].w * h4.w;
                    }
                    g1_lds[nb * G4 + g] = a + s;
                }
            }
        }
        __syncthreads();
        // ---- combine phase ----
        {
            const float* gl = isL1 ? g1_lds : g0_lds;
            float* hl = isL1 ? h1_lds : h0_lds;
            const bool active = isL1 ? (it >= 1) : (it < TT);
            if (active) {
                // cell 0: k = ck
                {
                    const int k = ck;
                    float gi = gl[cnb * G4 + k];
                    float gf = gl[cnb * G4 + 64 + k];
                    float gg = gl[cnb * G4 + 128 + k];
                    float go = gl[cnb * G4 + 192 + k];
                    float c = sigf(gf) * c_s0 + sigf(gi) * tanh_fast(gg);
                    c_s0 = c;
                    float h = sigf(go) * tanh_fast(c);
                    hl[cnb * HH + k] = h;
                    if (isL1 && it == TT) x_out[(n0 + cnb) * HH + k] = h;
                }
                // cell 1: k = ck + 32
                {
                    const int k = ck + 32;
                    float gi = gl[cnb * G4 + k];
                    float gf = gl[cnb * G4 + 64 + k];
                    float gg = gl[cnb * G4 + 128 + k];
                    float go = gl[cnb * G4 + 192 + k];
                    float c = sigf(gf) * c_s1 + sigf(gi) * tanh_fast(gg);
                    c_s1 = c;
                    float h = sigf(go) * tanh_fast(c);
                    hl[cnb * HH + k] = h;
                    if (isL1 && it == TT) x_out[(n0 + cnb) * HH + k] = h;
                }
            }
        }
        __syncthreads();
    }
}

// ---------- row_full: 1 if row i of rel_mask has NO edge (fallback: softmax over all -1e9 row -> all adj true) ----------
__global__ void k_rowmask(const float* __restrict__ rel_mask, int* __restrict__ row_full)
{
    const int i = blockIdx.x;
    const int tid = threadIdx.x;
    bool found = false;
    for (int j = tid; j < NN; j += 256)
        found |= (rel_mask[i * NN + j] == 0.0f);
    __shared__ int s_any;
    if (tid == 0) s_any = 0;
    __syncthreads();
    if (found) atomicOr(&s_any, 1);
    __syncthreads();
    if (tid == 0) row_full[i] = s_any ? 0 : 1;
}

// ---------- h1 = x @ gat1_W ; es1/ed1 dots ----------
// 16 nodes per block, 256 threads: (ln = tid>>4, j = tid&15)
__global__ __launch_bounds__(256) void k_h1(
    const float* __restrict__ x, const float* __restrict__ W,
    const float* __restrict__ a_s, const float* __restrict__ a_d,
    float* __restrict__ h1g, float* __restrict__ es1, float* __restrict__ ed1)
{
    __shared__ float Wl[HH * GATH];     // 1024
    __shared__ float xl[16 * 65];       // padded
    __shared__ float h1l[16 * GATH];
    const int tid = threadIdx.x;
    const int n0 = blockIdx.x * 16;
    for (int idx = tid; idx < HH * GATH; idx += 256) Wl[idx] = W[idx];
    for (int idx = tid; idx < 16 * HH; idx += 256) {
        int ln = idx >> 6, k = idx & 63;
        xl[ln * 65 + k] = x[(n0 + ln) * HH + k];
    }
    __syncthreads();
    const int ln = tid >> 4, jj = tid & 15;
    float acc = 0.0f;
    #pragma unroll 8
    for (int k = 0; k < HH; ++k) acc += xl[ln * 65 + k] * Wl[k * GATH + jj];
    h1g[(n0 + ln) * GATH + jj] = acc;
    h1l[ln * GATH + jj] = acc;
    __syncthreads();
    if (tid < 16) {
        float e_s = 0.0f, e_d = 0.0f;
        #pragma unroll
        for (int t = 0; t < GATH; ++t) {
            float hv = h1l[tid * GATH + t];
            e_s += hv * a_s[t];
            e_d += hv * a_d[t];
        }
        es1[n0 + tid] = e_s;
        ed1[n0 + tid] = e_d;
    }
}

// ---------- GAT1: column softmax (axis 0) + aggregate + relu ----------
// block: 8 columns x 32 row-partitions
__global__ __launch_bounds__(256) void k_gat1(
    const float* __restrict__ rel_mask, const int* __restrict__ row_full,
    const float* __restrict__ h1g, const float* __restrict__ es1,
    const float* __restrict__ ed1, const float* __restrict__ gat1_b,
    float* __restrict__ hrel)
{
    const int tid = threadIdx.x;
    const int c = tid & 7;
    const int r = tid >> 3;
    const int j = blockIdx.x * 8 + c;
    const float edj = ed1[j];
    float l = 0.0f;
    float o[GATH];
    #pragma unroll
    for (int t = 0; t < GATH; ++t) o[t] = 0.0f;

    for (int i = r; i < NN; i += 32) {
        float rm = rel_mask[i * NN + j];
        bool adj = (rm == 0.0f) || (i == j) || (row_full[i] != 0);
        if (adj) {
            float e = es1[i] + edj;
            e = (e > 0.0f) ? e : 0.2f * e;
            float p = __expf(e);   // no max-subtraction needed: |e| is O(1)
            l += p;
            const float4* hv = (const float4*)(h1g + i * GATH);
            #pragma unroll
            for (int q = 0; q < 4; ++q) {
                float4 h4 = hv[q];
                o[4 * q + 0] += p * h4.x;
                o[4 * q + 1] += p * h4.y;
                o[4 * q + 2] += p * h4.z;
                o[4 * q + 3] += p * h4.w;
            }
        }
    }
    __shared__ float s_l[256];
    __shared__ float s_o[256 * GATH];
    s_l[c * 32 + r] = l;
    #pragma unroll
    for (int t = 0; t < GATH; ++t) s_o[(c * 32 + r) * GATH + t] = o[t];
    __syncthreads();
    for (int step = 16; step >= 1; step >>= 1) {
        if (r < step) {
            int a = c * 32 + r, b = a + step;
            s_l[a] += s_l[b];
            #pragma unroll
            for (int t = 0; t < GATH; ++t) s_o[a * GATH + t] += s_o[b * GATH + t];
        }
        __syncthreads();
    }
    if (tid < 128) {
        int cc = tid >> 4, jj = tid & 15;
        float v = s_o[(cc * 32) * GATH + jj] / s_l[cc * 32] + gat1_b[jj];
        hrel[(blockIdx.x * 8 + cc) * GATH + jj] = fmaxf(v, 0.0f);
    }
}

// ---------- h2 = hrel @ gat2_W ; es2/ed2 ----------
// 4 nodes per block, 256 threads: (ln = tid>>6, j = tid&63)
__global__ __launch_bounds__(256) void k_h2(
    const float* __restrict__ hrel, const float* __restrict__ W2,
    const float* __restrict__ a_s, const float* __restrict__ a_d,
    float* __restrict__ h2g, float* __restrict__ es2, float* __restrict__ ed2)
{
    __shared__ float Wl[GATH * HH];    // 1024
    __shared__ float hl[4 * 17];       // padded
    __shared__ float h2l[4 * HH];
    const int tid = threadIdx.x;
    const int n0 = blockIdx.x * 4;
    for (int idx = tid; idx < GATH * HH; idx += 256) Wl[idx] = W2[idx];
    if (tid < 64) {
        int ln = tid >> 4, k = tid & 15;
        hl[ln * 17 + k] = hrel[(n0 + ln) * GATH + k];
    }
    __syncthreads();
    const int ln = tid >> 6, jj = tid & 63;
    float acc = 0.0f;
    #pragma unroll
    for (int k = 0; k < GATH; ++k) acc += hl[ln * 17 + k] * Wl[k * HH + jj];
    h2g[(n0 + ln) * HH + jj] = acc;
    h2l[ln * HH + jj] = acc;
    __syncthreads();
    if (tid < 4) {
        float e_s = 0.0f, e_d = 0.0f;
        #pragma unroll 16
        for (int t = 0; t < HH; ++t) {
            float hv = h2l[tid * HH + t];
            e_s += hv * a_s[t];
            e_d += hv * a_d[t];
        }
        es2[n0 + tid] = e_s;
        ed2[n0 + tid] = e_d;
    }
}

// ---------- GAT2 + fc + leaky_relu ----------
__global__ __launch_bounds__(256) void k_gat2(
    const float* __restrict__ rel_mask, const int* __restrict__ row_full,
    const float* __restrict__ h2g, const float* __restrict__ es2,
    const float* __restrict__ ed2, const float* __restrict__ gat2_b,
    const float* __restrict__ fc_W, const float* __restrict__ fc_b,
    float* __restrict__ out)
{
    const int tid = threadIdx.x;
    const int c = tid & 7;
    const int r = tid >> 3;
    const int j = blockIdx.x * 8 + c;
    const float edj = ed2[j];
    float l = 0.0f;
    float o[HH];
    #pragma unroll
    for (int t = 0; t < HH; ++t) o[t] = 0.0f;

    for (int i = r; i < NN; i += 32) {
        float rm = rel_mask[i * NN + j];
        bool adj = (rm == 0.0f) || (i == j) || (row_full[i] != 0);
        if (adj) {
            float e = es2[i] + edj;
            e = (e > 0.0f) ? e : 0.2f * e;
            float p = __expf(e);
            l += p;
            const float4* hv = (const float4*)(h2g + (size_t)i * HH);
            #pragma unroll
            for (int q = 0; q < 16; ++q) {
                float4 h4 = hv[q];
                o[4 * q + 0] += p * h4.x;
                o[4 * q + 1] += p * h4.y;
                o[4 * q + 2] += p * h4.z;
                o[4 * q + 3] += p * h4.w;
            }
        }
    }
    __shared__ float s_l[256];
    __shared__ float s_o[256 * HH];   // 64 KB
    s_l[c * 32 + r] = l;
    #pragma unroll
    for (int t = 0; t < HH; ++t) s_o[(c * 32 + r) * HH + t] = o[t];
    __syncthreads();
    for (int step = 16; step >= 1; step >>= 1) {
        if (r < step) {
            int a = c * 32 + r, b = a + step;
            s_l[a] += s_l[b];
            #pragma unroll
            for (int t = 0; t < HH; ++t) s_o[a * HH + t] += s_o[b * HH + t];
        }
        __syncthreads();
    }
    __shared__ float s_out[8 * HH];
    {
        int cc = tid >> 5, jj = tid & 31;
        float linv = 1.0f / s_l[cc * 32];
        s_out[cc * HH + jj] = s_o[(cc * 32) * HH + jj] * linv + gat2_b[jj];
        s_out[cc * HH + jj + 32] = s_o[(cc * 32) * HH + jj + 32] * linv + gat2_b[jj + 32];
    }
    __syncthreads();
    if (tid < 8) {
        float acc = fc_b[0];
        #pragma unroll 16
        for (int t = 0; t < HH; ++t) acc += s_out[tid * HH + t] * fc_W[t];
        out[blockIdx.x * 8 + tid] = (acc > 0.0f) ? acc : 0.2f * acc;
    }
}

extern "C" void kernel_launch(void* const* d_in, const int* in_sizes, int n_in,
                              void* d_out, int out_size, void* d_ws, size_t ws_size,
                              hipStream_t stream)
{
    const float* inputs   = (const float*)d_in[0];
    // d_in[1] (relation), d_in[3] (rel_w_W), d_in[4] (rel_w_b) are dead:
    // softmax(rel_mask + weight) > 0 depends only on rel_mask (see analysis).
    const float* rel_mask = (const float*)d_in[2];
    const float* w_ih0 = (const float*)d_in[5];
    const float* w_hh0 = (const float*)d_in[6];
    const float* b_ih0 = (const float*)d_in[7];
    const float* b_hh0 = (const float*)d_in[8];
    const float* w_ih1 = (const float*)d_in[9];
    const float* w_hh1 = (const float*)d_in[10];
    const float* b_ih1 = (const float*)d_in[11];
    const float* b_hh1 = (const float*)d_in[12];
    const float* gat1_W  = (const float*)d_in[13];
    const float* gat1_as = (const float*)d_in[14];
    const float* gat1_ad = (const float*)d_in[15];
    const float* gat1_b  = (const float*)d_in[16];
    const float* gat2_W  = (const float*)d_in[17];
    const float* gat2_as = (const float*)d_in[18];
    const float* gat2_ad = (const float*)d_in[19];
    const float* gat2_b  = (const float*)d_in[20];
    const float* fc_W = (const float*)d_in[21];
    const float* fc_b = (const float*)d_in[22];
    float* out = (float*)d_out;

    float* ws = (float*)d_ws;
    float* x_out = ws;                       // 2048*64
    float* h1g = x_out + NN * HH;            // 2048*16
    float* es1 = h1g + NN * GATH;            // 2048
    float* ed1 = es1 + NN;                   // 2048
    float* hrel = ed1 + NN;                  // 2048*16
    float* h2g = hrel + NN * GATH;           // 2048*64
    float* es2 = h2g + NN * HH;              // 2048
    float* ed2 = es2 + NN;                   // 2048
    int* row_full = (int*)(ed2 + NN);        // 2048

    k_lstm<<<NN / LNB, 512, 0, stream>>>(inputs, w_ih0, w_hh0, b_ih0, b_hh0,
                                         w_ih1, w_hh1, b_ih1, b_hh1, x_out);
    k_rowmask<<<NN, 256, 0, stream>>>(rel_mask, row_full);
    k_h1<<<NN / 16, 256, 0, stream>>>(x_out, gat1_W, gat1_as, gat1_ad, h1g, es1, ed1);
    k_gat1<<<NN / 8, 256, 0, stream>>>(rel_mask, row_full, h1g, es1, ed1, gat1_b, hrel);
    k_h2<<<NN / 4, 256, 0, stream>>>(hrel, gat2_W, gat2_as, gat2_ad, h2g, es2, ed2);
    k_gat2<<<NN / 8, 256, 0, stream>>>(rel_mask, row_full, h2g, es2, ed2, gat2_b,
                                       fc_W, fc_b, out);
}